// Round 1
// baseline (254.734 us; speedup 1.0000x reference)
//
#include <hip/hip_runtime.h>
#include <math.h>

// Problem constants (fixed by the reference).
#define Bsz 64
#define Ssz 14
#define Isz 32
#define Csz 10
#define Dsz 16
#define Nsz (Ssz*Ssz*Isz)   // 6272
#define EPSF 1e-9f

#define CH   640            // em chunk: n's per block (== block size)
#define NCH  10             // ceil(6272/640); chunk 9 has 512 valid n
#define MCH  3136           // moment-kernel chunk (2 per b); 3136 % 32 == 0
#define PST  36             // prm row stride (floats): mean16 | invd16 | K | pad
#define MST  72             // moment row stride (floats): 69 used + pad

// ---------------------------------------------------------------------------
// DPP wave64 sum: row_shr 1/2/4/8 then row_bcast 15/31. Total lands in lane 63.
// VALU-pipe only -- replaces the ds_swizzle butterfly (198 LDS ops per wave).
// ---------------------------------------------------------------------------
template<int CTRL, int RMASK>
__device__ __forceinline__ float dpp_add(float x) {
    int y = __builtin_amdgcn_update_dpp(0, __float_as_int(x), CTRL, RMASK, 0xf, true);
    return x + __int_as_float(y);
}
__device__ __forceinline__ float wave_sum64(float x) {
    x = dpp_add<0x111, 0xf>(x);   // row_shr:1
    x = dpp_add<0x112, 0xf>(x);   // row_shr:2
    x = dpp_add<0x114, 0xf>(x);   // row_shr:4
    x = dpp_add<0x118, 0xf>(x);   // row_shr:8  -> lane15 of each row = row sum
    x = dpp_add<0x142, 0xa>(x);   // row_bcast:15 into rows 1,3
    x = dpp_add<0x143, 0xc>(x);   // row_bcast:31 into rows 2,3 -> lane63 = total
    return x;
}

// ---------------------------------------------------------------------------
// mom_kernel: iteration-0 M-step via class-independent per-i pose moments.
// With uniform rr the weight w_n = act_n/C is class-independent, so
//   S1[c,d] = sum_i  W[i,c] . M1_i   (+coord),   S2 via second moments M2_i.
// Each thread owns a fixed i (= tid&31 since all n-strides are mult. of 32)
// and accumulates 69 moments in registers; fold lane<->lane+32; ds_add across
// waves; write [b][mch][32][MST] to global.
// Moment layout per i: [0]=S0 [1..16]=Sp [17..56]=Spp(pr-major, pairs k<=k')
//                      [57..60]=Sh [61..64]=Sw [65]=Sch [66]=Scw [67]=Shh [68]=Sww
// ---------------------------------------------------------------------------
__global__ __launch_bounds__(640) void mom_kernel(
    const float* __restrict__ pose,     // [B][N][16]
    const float* __restrict__ act,      // [B][N]
    float* __restrict__ partM)          // [B][2][32][MST]
{
    const int b = blockIdx.x, mch = blockIdx.y;
    const int tid = threadIdx.x, lane = tid & 63;

    __shared__ float Macc[32][73];      // stride 73: conflict-free ds_add

    float s[69];
#pragma unroll
    for (int j = 0; j < 69; ++j) s[j] = 0.f;

    const float* poseb = pose + (size_t)b*Nsz*Dsz;
    const float* actb  = act  + (size_t)b*Nsz;
    const int base = mch*MCH;

    for (int k = 0; k < MCH; k += 640) {
        const int nl = k + tid;
        if (nl < MCH) {
            const int n = base + nl;    // i = n&31 = tid&31 (all strides %32==0)
            const float4* pp = reinterpret_cast<const float4*>(poseb + (size_t)n*Dsz);
            float4 a0 = pp[0], a1 = pp[1], a2 = pp[2], a3 = pp[3];
            float p[16] = {a0.x,a0.y,a0.z,a0.w, a1.x,a1.y,a1.z,a1.w,
                           a2.x,a2.y,a2.z,a2.w, a3.x,a3.y,a3.z,a3.w};
            const int hw = n >> 5;
            const int wc = hw % Ssz, hr = hw / Ssz;
            const float chh = (hr+0.5f)*(1.0f/Ssz), cww = (wc+0.5f)*(1.0f/Ssz);
            const float wgt = actb[n]*(1.0f/Csz);
            s[0] += wgt;
            float wp[16];
#pragma unroll
            for (int j = 0; j < 16; ++j) { wp[j] = wgt*p[j]; s[1+j] += wp[j]; }
            int t = 17;                 // fully unrolled -> constant indices
#pragma unroll
            for (int pr = 0; pr < 4; ++pr)
#pragma unroll
                for (int k1 = 0; k1 < 4; ++k1)
#pragma unroll
                    for (int k2 = k1; k2 < 4; ++k2)
                        s[t++] += wp[pr*4+k1]*p[pr*4+k2];
            const float wch = wgt*chh, wcw = wgt*cww;
#pragma unroll
            for (int j = 0; j < 4; ++j) { s[57+j] += wch*p[j]; s[61+j] += wcw*p[j]; }
            s[65] += wch; s[66] += wcw; s[67] += wch*chh; s[68] += wcw*cww;
        }
    }
    // lane and lane+32 share the same i -> fold
#pragma unroll
    for (int j = 0; j < 69; ++j) s[j] += __shfl_xor(s[j], 32);

    for (int t = tid; t < 32*73; t += 640) (&Macc[0][0])[t] = 0.f;
    __syncthreads();
    if (lane < 32) {
#pragma unroll
        for (int j = 0; j < 69; ++j) atomicAdd(&Macc[lane][j], s[j]);
    }
    __syncthreads();
    float* ob = partM + (size_t)(b*2 + mch)*32*MST;
    for (int t = tid; t < 32*MST; t += 640) {
        const int i = t / MST, j = t - i*MST;
        ob[t] = (j < 69) ? Macc[i][j] : 0.f;
    }
}

// ---------------------------------------------------------------------------
// fin0: per b, reduce the 2 moment chunks, transform through W to per-class
// S0/S1/S2, then mean/var/cost/oact (inv_temp) -> prm[b][c] = {mean,invd,K}.
// Pair order t: (00)(01)(02)(03)(11)(12)(13)(22)(23)(33).
// ---------------------------------------------------------------------------
__global__ __launch_bounds__(256) void fin0_kernel(
    const float* __restrict__ partM,
    const float* __restrict__ w,        // [I][C][16]
    const float* __restrict__ beta_v, const float* __restrict__ beta_a,
    float* __restrict__ prm, float inv_temp)
{
    const int b = blockIdx.x, tid = threadIdx.x;
    __shared__ float Mr[32][73];
    __shared__ float Ws[Isz*Csz*Dsz];
    __shared__ float pm[Csz][16], pg[Csz][16], pl[Csz][16];
    __shared__ float s0sh;

    const float* p0 = partM + (size_t)(b*2 + 0)*32*MST;
    const float* p1 = partM + (size_t)(b*2 + 1)*32*MST;
    for (int t = tid; t < 32*MST; t += 256) {
        const int i = t / MST, j = t - i*MST;
        Mr[i][j] = p0[t] + p1[t];
    }
    for (int t = tid; t < Isz*Csz*Dsz; t += 256) Ws[t] = w[t];
    __syncthreads();

    if (tid < Csz*Dsz) {
        const int c = tid >> 4, d = tid & 15, pr = d >> 2, r = d & 3;
        float S0 = 0.f, S1 = 0.f, S2 = 0.f;
        for (int i = 0; i < 32; ++i) {
            const float* Wi = Ws + (i*Csz + c)*Dsz;
            const float* Mi = Mr[i];
            S0 += Mi[0];
            const float w0 = Wi[0*4+r], w1 = Wi[1*4+r], w2 = Wi[2*4+r], w3 = Wi[3*4+r];
            const float* M1 = Mi + 1 + pr*4;
            S1 += w0*M1[0] + w1*M1[1] + w2*M1[2] + w3*M1[3];
            const float* Q = Mi + 17 + pr*10;
            S2 += w0*w0*Q[0] + w1*w1*Q[4] + w2*w2*Q[7] + w3*w3*Q[9]
                + 2.f*(w0*w1*Q[1] + w0*w2*Q[2] + w0*w3*Q[3]
                     + w1*w2*Q[5] + w1*w3*Q[6] + w2*w3*Q[8]);
            if (d == 0) {
                S1 += Mi[65];
                S2 += 2.f*(w0*Mi[57] + w1*Mi[58] + w2*Mi[59] + w3*Mi[60]) + Mi[67];
            } else if (d == 1) {
                S1 += Mi[66];
                S2 += 2.f*(w0*Mi[61] + w1*Mi[62] + w2*Mi[63] + w3*Mi[64]) + Mi[68];
            }
        }
        const float mean = S1 / S0;
        const float var = fmaxf(S2/S0 - mean*mean, 0.f);
        pm[c][d] = mean;
        pg[c][d] = 1.f/(2.f*var + EPSF);
        pl[c][d] = __logf(sqrtf(var) + EPSF);
        if (tid == 0) s0sh = S0;        // S0 identical for all classes at it=0
    }
    __syncthreads();
    if (tid < Csz) {
        const int c = tid;
        float sumlog = 0.f;
#pragma unroll
        for (int d = 0; d < 16; ++d) sumlog += pl[c][d];
        const float cost = s0sh*(16.f*beta_v[c] + sumlog);
        const float oact = 1.f/(1.f + __expf(-inv_temp*(beta_a[c] - cost)));
        const float K = __logf(oact + EPSF) - sumlog;
        float* o = prm + (size_t)(b*Csz + c)*PST;
#pragma unroll
        for (int d = 0; d < 16; ++d) { o[d] = pm[c][d]; o[16+d] = pg[c][d]; }
        o[32] = K;
    }
}

// ---------------------------------------------------------------------------
// em_kernel: E (thread-per-n, prm via wave-uniform scalar loads from global)
// + M (wave-per-class, W hoisted to registers, DPP reduction, no butterfly).
// Writes class partials in fin-coalesced layout partC[chunk][33][640].
// ---------------------------------------------------------------------------
__global__ __launch_bounds__(640) void em_kernel(
    const float* __restrict__ pose, const float* __restrict__ act,
    const float* __restrict__ w, const float* __restrict__ prm,
    float* __restrict__ partC)          // [NCH][33][B*C]
{
    const int b = blockIdx.x, chunk = blockIdx.y;
    const int tid = threadIdx.x, wv = tid >> 6, lane = tid & 63;

    __shared__ float Wm[Csz][Isz*17];   // stride 17 -> conflict-free
    __shared__ float rr[Csz][CH];

    for (int t = tid; t < Csz*Isz*Dsz; t += 640) {
        const int cc = t >> 9, rem = t & 511, i = rem >> 4, q = rem & 15;
        Wm[cc][i*17 + q] = w[(i*Csz + cc)*Dsz + q];
    }
    __syncthreads();

    const int base = chunk*CH;
    const float* poseb = pose + (size_t)b*Nsz*Dsz;

    {   // ---- E phase: one n per thread ----
        const int n = base + tid;
        if (n < Nsz) {
            const float4* pp = reinterpret_cast<const float4*>(poseb + (size_t)n*Dsz);
            float4 a0 = pp[0], a1 = pp[1], a2 = pp[2], a3 = pp[3];
            float p[16] = {a0.x,a0.y,a0.z,a0.w, a1.x,a1.y,a1.z,a1.w,
                           a2.x,a2.y,a2.z,a2.w, a3.x,a3.y,a3.z,a3.w};
            const int i = tid & 31;
            const int hw = n >> 5;
            const int wc = hw % Ssz, hr = hw / Ssz;
            const float chh = (hr+0.5f)*(1.0f/Ssz), cww = (wc+0.5f)*(1.0f/Ssz);
            const float a = act[(size_t)b*Nsz + n];
            float zz[Csz];
#pragma unroll
            for (int c = 0; c < Csz; ++c) {
                const float* __restrict__ Wi = &Wm[c][i*17];
                const float* __restrict__ pg = prm + (size_t)(b*Csz + c)*PST; // uniform -> s_load
                float quad = 0.f;
#pragma unroll
                for (int pr = 0; pr < 4; ++pr) {
#pragma unroll
                    for (int r = 0; r < 4; ++r) {
                        float vv = p[pr*4+0]*Wi[0*4+r] + p[pr*4+1]*Wi[1*4+r]
                                 + p[pr*4+2]*Wi[2*4+r] + p[pr*4+3]*Wi[3*4+r];
                        if (pr == 0 && r == 0) vv += chh;
                        if (pr == 0 && r == 1) vv += cww;
                        const int d = pr*4 + r;
                        const float dv = vv - pg[d];
                        quad += dv*dv*pg[16+d];
                    }
                }
                zz[c] = pg[32] - quad;
            }
            float zmax = zz[0];
#pragma unroll
            for (int c = 1; c < Csz; ++c) zmax = fmaxf(zmax, zz[c]);
            float zsum = 0.f;
#pragma unroll
            for (int c = 0; c < Csz; ++c) { zz[c] = __expf(zz[c] - zmax); zsum += zz[c]; }
            const float sc = __fdividef(a, zsum);
#pragma unroll
            for (int c = 0; c < Csz; ++c) rr[c][tid] = zz[c]*sc;
        }
    }
    __syncthreads();

    // ---- M phase: wave = class; i = lane&31 constant -> W in registers ----
    const int c = wv;
    float W16[16];
#pragma unroll
    for (int j = 0; j < 16; ++j) W16[j] = Wm[c][(lane & 31)*17 + j];

    float s0 = 0.f, s1[16], s2[16];
#pragma unroll
    for (int d = 0; d < 16; ++d) { s1[d] = 0.f; s2[d] = 0.f; }

    for (int k = 0; k < CH; k += 64) {
        const int nl = k + lane;
        const int n = base + nl;
        if (n < Nsz) {
            const float4* pp = reinterpret_cast<const float4*>(poseb + (size_t)n*Dsz);
            const int hw = n >> 5;
            const int wc2 = hw % Ssz, hr2 = hw / Ssz;
            const float chh = (hr2+0.5f)*(1.0f/Ssz), cww = (wc2+0.5f)*(1.0f/Ssz);
            const float wgt = rr[c][nl];
            s0 += wgt;
#pragma unroll
            for (int pr = 0; pr < 4; ++pr) {
                const float4 pv = pp[pr];
#pragma unroll
                for (int r = 0; r < 4; ++r) {
                    float vv = pv.x*W16[0*4+r] + pv.y*W16[1*4+r]
                             + pv.z*W16[2*4+r] + pv.w*W16[3*4+r];
                    if (pr == 0 && r == 0) vv += chh;
                    if (pr == 0 && r == 1) vv += cww;
                    const float wvv = wgt*vv;
                    s1[pr*4+r] += wvv;
                    s2[pr*4+r] += wvv*vv;
                }
            }
        }
    }
    s0 = wave_sum64(s0);
#pragma unroll
    for (int d = 0; d < 16; ++d) { s1[d] = wave_sum64(s1[d]); s2[d] = wave_sum64(s2[d]); }
    if (lane == 63) {
        const int bc = b*Csz + c;
        float* pt = partC + (size_t)chunk*33*(Bsz*Csz) + bc;
        pt[0] = s0;
#pragma unroll
        for (int d = 0; d < 16; ++d) {
            pt[(size_t)(1+d)*(Bsz*Csz)]  = s1[d];
            pt[(size_t)(17+d)*(Bsz*Csz)] = s2[d];
        }
    }
}

// ---------------------------------------------------------------------------
// fin12: thread per (b,c): reduce class partials over chunks (coalesced),
// compute mean/var/cost/oact. Mid-iterations write prm; last writes outputs.
// ---------------------------------------------------------------------------
__global__ __launch_bounds__(64) void fin12_kernel(
    const float* __restrict__ partC, const float* __restrict__ beta_v,
    const float* __restrict__ beta_a, float* __restrict__ prm,
    float* __restrict__ out, float inv_temp)
{
    const int bc = blockIdx.x*64 + threadIdx.x;   // grid exact: 640 threads
    const int c = bc % Csz;
    float S[33];
#pragma unroll
    for (int j = 0; j < 33; ++j) S[j] = 0.f;
    for (int ch = 0; ch < NCH; ++ch) {
        const float* pb = partC + (size_t)ch*33*(Bsz*Csz) + bc;
#pragma unroll
        for (int j = 0; j < 33; ++j) S[j] += pb[(size_t)j*(Bsz*Csz)];
    }
    const float S0 = S[0], rS0 = 1.f/S0;
    float mean[16], gv[16];
    float sumlog = 0.f;
#pragma unroll
    for (int d = 0; d < 16; ++d) {
        const float mn = S[1+d]*rS0;
        const float var = fmaxf(S[17+d]*rS0 - mn*mn, 0.f);
        mean[d] = mn;
        gv[d] = 1.f/(2.f*var + EPSF);
        sumlog += __logf(sqrtf(var) + EPSF);
    }
    const float cost = S0*(16.f*beta_v[c] + sumlog);
    const float oact = 1.f/(1.f + __expf(-inv_temp*(beta_a[c] - cost)));
    if (out) {
#pragma unroll
        for (int d = 0; d < 16; ++d) out[(size_t)bc*16 + d] = mean[d];
        out[(size_t)Bsz*Csz*Dsz + bc] = oact;
    } else {
        const float K = __logf(oact + EPSF) - sumlog;
        float* o = prm + (size_t)bc*PST;
#pragma unroll
        for (int d = 0; d < 16; ++d) { o[d] = mean[d]; o[16+d] = gv[d]; }
        o[32] = K;
    }
}

// ---------------------------------------------------------------------------
// 6 dispatches: mom -> fin0 -> EM1 -> fin1 -> EM2 -> fin2(out).
// Workspace: partM 294912 fl (aliased by partC 211200 fl: mom/fin0 done before
// em1 writes) + prmA/prmB 23040 fl each = 1.36 MB total (< previous 1.69 MB).
// ---------------------------------------------------------------------------
extern "C" void kernel_launch(void* const* d_in, const int* in_sizes, int n_in,
                              void* d_out, int out_size, void* d_ws, size_t ws_size,
                              hipStream_t stream)
{
    const float* pose = (const float*)d_in[0];
    const float* act  = (const float*)d_in[1];
    const float* w    = (const float*)d_in[2];
    const float* bv   = (const float*)d_in[3];
    const float* ba   = (const float*)d_in[4];
    float* out = (float*)d_out;

    float* partM = (float*)d_ws;                       // [64][2][32][72]
    float* partC = partM;                              // alias, sequential reuse
    float* prmA  = partM + (size_t)Bsz*2*32*MST;
    float* prmB  = prmA + (size_t)Bsz*Csz*PST;

    mom_kernel  <<<dim3(Bsz, 2),   640, 0, stream>>>(pose, act, partM);
    fin0_kernel <<<Bsz,            256, 0, stream>>>(partM, w, bv, ba, prmA, 1.0f);
    em_kernel   <<<dim3(Bsz, NCH), 640, 0, stream>>>(pose, act, w, prmA, partC);
    fin12_kernel<<<(Bsz*Csz)/64,    64, 0, stream>>>(partC, bv, ba, prmB, nullptr, 2.0f);
    em_kernel   <<<dim3(Bsz, NCH), 640, 0, stream>>>(pose, act, w, prmB, partC);
    fin12_kernel<<<(Bsz*Csz)/64,    64, 0, stream>>>(partC, bv, ba, nullptr, out, 3.0f);
}